// Round 1
// baseline (140.737 us; speedup 1.0000x reference)
//
#include <hip/hip_runtime.h>
#include <hip/hip_bf16.h>
#include <stdint.h>

#define DD 120
#define HH 8
#define HD 15
#define KP 128         // K padded to 128
#define N1 360         // 3*D
#define N1P 368        // qkv N padded (23 tiles of 16)
#define NT1 23
#define LN_EPS 1e-5f

typedef __attribute__((ext_vector_type(8))) short bf16x8;
typedef __attribute__((ext_vector_type(4))) float f32x4;

__device__ __forceinline__ unsigned short f2bf(float f) {
    union { float f; unsigned u; } v; v.f = f;
    unsigned u = v.u + 0x7FFFu + ((v.u >> 16) & 1u);   // RNE
    return (unsigned short)(u >> 16);
}
__device__ __forceinline__ float bf2f(unsigned short h) {
    union { unsigned u; float f; } v; v.u = ((unsigned)h) << 16;
    return v.f;
}

// ---- prep: convert weights to bf16, pad to MFMA-friendly shapes, in ws ----
// W1b: [368][128] bf16  (row n = output channel, k contiguous)  = in_proj_w padded
// W2b: [128][128] bf16  = out_w padded
__global__ void prep_weights(const float* __restrict__ w1, const float* __restrict__ w2,
                             unsigned short* __restrict__ W1b, unsigned short* __restrict__ W2b) {
    int idx = blockIdx.x * blockDim.x + threadIdx.x;
    int stride = gridDim.x * blockDim.x;
    for (int i = idx; i < N1P * KP; i += stride) {
        int n = i >> 7, k = i & 127;
        unsigned short v = 0;
        if (n < N1 && k < DD) v = f2bf(w1[n * DD + k]);
        W1b[i] = v;
    }
    for (int i = idx; i < KP * KP; i += stride) {
        int n = i >> 7, k = i & 127;
        unsigned short v = 0;
        if (n < DD && k < DD) v = f2bf(w2[n * DD + k]);
        W2b[i] = v;
    }
}

// ---- fused kernel: 32 locations (64 tokens) per workgroup of 256 threads ----
__global__ __launch_bounds__(256) void fused_attn(
    const float* __restrict__ voxel, const float* __restrict__ cnnf,
    const float* __restrict__ in_b, const float* __restrict__ out_b,
    const float* __restrict__ gamma, const float* __restrict__ beta,
    const unsigned short* __restrict__ W1b, const unsigned short* __restrict__ W2b,
    float* __restrict__ out)
{
    // LDS: xo = [64][128] bf16 swizzled A-tile (x, later o)          16384 B
    //      qkv = [64][368] bf16                                      47104 B
    //      ylds = [64][124] f32  (overlays qkv region)               31744 B
    __shared__ __align__(16) char smem[16384 + 47104];
    unsigned short* xo  = (unsigned short*)smem;
    unsigned short* qkv = (unsigned short*)(smem + 16384);
    float* ylds = (float*)(smem + 16384);

    const int tid = threadIdx.x;
    const int loc0 = blockIdx.x * 32;

    // ---------- phase 1: stage x (voxel/cnn interleaved) -> bf16 swizzled LDS ----------
    // 64 rows x 30 float4-chunks
    for (int i = tid; i < 64 * 30; i += 256) {
        int r = i / 30, c4 = i % 30;
        const float* src = ((r & 1) ? cnnf : voxel) + (size_t)(loc0 + (r >> 1)) * DD + c4 * 4;
        float4 f = *(const float4*)src;
        ushort4 h;
        h.x = f2bf(f.x); h.y = f2bf(f.y); h.z = f2bf(f.z); h.w = f2bf(f.w);
        int c8 = c4 >> 1, sub = (c4 & 1) * 8;
        *(ushort4*)((char*)xo + r * 256 + ((c8 ^ (r & 7)) << 4) + sub) = h;
    }
    // zero the K-pad chunk (cols 120..127) of every row
    for (int r = tid; r < 64; r += 256) {
        *(uint4*)((char*)xo + r * 256 + ((15 ^ (r & 7)) << 4)) = make_uint4(0, 0, 0, 0);
    }
    __syncthreads();

    const int wave = tid >> 6, lane = tid & 63;
    const int lrow = lane & 15;       // A-row / B-col within tile
    const int lk   = lane >> 4;       // k-slice 0..3

    // ---------- phase 2: QKV GEMM (A=x 64x128, B=W1b^T via [n][k] rows) ----------
    {
        bf16x8 afrag[4][4];
        #pragma unroll
        for (int m = 0; m < 4; ++m) {
            int r = m * 16 + lrow;
            #pragma unroll
            for (int kk = 0; kk < 4; ++kk) {
                int chunk = kk * 4 + lk;
                afrag[m][kk] = *(const bf16x8*)((const char*)xo + r * 256 + ((chunk ^ (r & 7)) << 4));
            }
        }
        for (int t = wave; t < NT1; t += 4) {
            int n = t * 16 + lrow;
            const unsigned short* brow = W1b + n * KP;
            bf16x8 bfrag[4];
            #pragma unroll
            for (int kk = 0; kk < 4; ++kk)
                bfrag[kk] = *(const bf16x8*)(brow + kk * 32 + lk * 8);
            float bias = (n < N1) ? in_b[n] : 0.f;
            #pragma unroll
            for (int m = 0; m < 4; ++m) {
                f32x4 acc = {0.f, 0.f, 0.f, 0.f};
                #pragma unroll
                for (int kk = 0; kk < 4; ++kk)
                    acc = __builtin_amdgcn_mfma_f32_16x16x32_bf16(afrag[m][kk], bfrag[kk], acc, 0, 0, 0);
                #pragma unroll
                for (int j = 0; j < 4; ++j) {
                    int row = m * 16 + lk * 4 + j;
                    qkv[row * N1P + n] = f2bf(acc[j] + bias);
                }
            }
        }
    }
    __syncthreads();

    // ---------- phase 3: tiny attention, 1 thread per (location, head) ----------
    {
        int locl = tid >> 3;
        int h = tid & 7;
        int r0 = locl * 2, r1 = r0 + 1;
        const unsigned short* p0 = qkv + r0 * N1P + h * HD;
        const unsigned short* p1 = qkv + r1 * N1P + h * HD;
        float q0[HD], k0v[HD], v0[HD], q1[HD], k1v[HD], v1[HD];
        #pragma unroll
        for (int i = 0; i < HD; ++i) {
            q0[i]  = bf2f(p0[i]);           q1[i]  = bf2f(p1[i]);
            k0v[i] = bf2f(p0[DD + i]);      k1v[i] = bf2f(p1[DD + i]);
            v0[i]  = bf2f(p0[2 * DD + i]);  v1[i]  = bf2f(p1[2 * DD + i]);
        }
        const float scale = 0.25819888974716112567f; // 1/sqrt(15)
        float s00 = 0, s01 = 0, s10 = 0, s11 = 0;
        #pragma unroll
        for (int i = 0; i < HD; ++i) {
            s00 += q0[i] * k0v[i]; s01 += q0[i] * k1v[i];
            s10 += q1[i] * k0v[i]; s11 += q1[i] * k1v[i];
        }
        s00 *= scale; s01 *= scale; s10 *= scale; s11 *= scale;
        float m0 = fmaxf(s00, s01), m1 = fmaxf(s10, s11);
        float e00 = __expf(s00 - m0), e01 = __expf(s01 - m0);
        float e10 = __expf(s10 - m1), e11 = __expf(s11 - m1);
        float d0 = e00 + e01, d1 = e10 + e11;
        float p00 = e00 / d0, p01 = e01 / d0, p10 = e10 / d1, p11 = e11 / d1;
        #pragma unroll
        for (int i = 0; i < HD; ++i) {
            float o0 = p00 * v0[i] + p01 * v1[i];
            float o1 = p10 * v0[i] + p11 * v1[i];
            int c = h * HD + i;
            int c8 = c >> 3, sub = (c & 7) * 2;
            *(unsigned short*)((char*)xo + r0 * 256 + ((c8 ^ (r0 & 7)) << 4) + sub) = f2bf(o0);
            *(unsigned short*)((char*)xo + r1 * 256 + ((c8 ^ (r1 & 7)) << 4) + sub) = f2bf(o1);
        }
        // note: pad chunk 15 (cols 120..127) still zero from phase 1 — untouched
    }
    __syncthreads();

    // ---------- phase 4: out projection (A=o 64x128, B=W2b) ----------
    {
        bf16x8 ofrag[4][4];
        #pragma unroll
        for (int m = 0; m < 4; ++m) {
            int r = m * 16 + lrow;
            #pragma unroll
            for (int kk = 0; kk < 4; ++kk) {
                int chunk = kk * 4 + lk;
                ofrag[m][kk] = *(const bf16x8*)((const char*)xo + r * 256 + ((chunk ^ (r & 7)) << 4));
            }
        }
        for (int t = wave; t < 8; t += 4) {
            int n = t * 16 + lrow;  // 0..127
            const unsigned short* brow = W2b + n * KP;
            bf16x8 bfrag[4];
            #pragma unroll
            for (int kk = 0; kk < 4; ++kk)
                bfrag[kk] = *(const bf16x8*)(brow + kk * 32 + lk * 8);
            float bias = (n < DD) ? out_b[n] : 0.f;
            #pragma unroll
            for (int m = 0; m < 4; ++m) {
                f32x4 acc = {0.f, 0.f, 0.f, 0.f};
                #pragma unroll
                for (int kk = 0; kk < 4; ++kk)
                    acc = __builtin_amdgcn_mfma_f32_16x16x32_bf16(ofrag[m][kk], bfrag[kk], acc, 0, 0, 0);
                if (n < DD) {
                    #pragma unroll
                    for (int j = 0; j < 4; ++j) {
                        int row = m * 16 + lk * 4 + j;
                        ylds[row * 124 + n] = acc[j] + bias;
                    }
                }
            }
        }
    }
    __syncthreads();

    // ---------- phase 5: LayerNorm + mean-pool, 8 threads per location ----------
    {
        int locl = tid >> 3, s = tid & 7;
        int r0 = locl * 2, r1 = r0 + 1;
        const float* y0 = ylds + r0 * 124 + s * HD;
        const float* y1 = ylds + r1 * 124 + s * HD;
        float a0[HD], a1[HD];
        float sum0 = 0, sq0 = 0, sum1 = 0, sq1 = 0;
        #pragma unroll
        for (int i = 0; i < HD; ++i) {
            a0[i] = y0[i]; a1[i] = y1[i];
            sum0 += a0[i]; sq0 += a0[i] * a0[i];
            sum1 += a1[i]; sq1 += a1[i] * a1[i];
        }
        #pragma unroll
        for (int w = 1; w < 8; w <<= 1) {
            sum0 += __shfl_xor(sum0, w);
            sq0  += __shfl_xor(sq0, w);
            sum1 += __shfl_xor(sum1, w);
            sq1  += __shfl_xor(sq1, w);
        }
        const float inv = 1.f / 120.f;
        float mu0 = sum0 * inv, mu1 = sum1 * inv;
        float var0 = sq0 * inv - mu0 * mu0, var1 = sq1 * inv - mu1 * mu1;
        float rs0 = rsqrtf(var0 + LN_EPS), rs1 = rsqrtf(var1 + LN_EPS);
        float* op = out + (size_t)(loc0 + locl) * DD + s * HD;
        #pragma unroll
        for (int i = 0; i < HD; ++i) {
            int d = s * HD + i;
            float g = gamma[d], b = beta[d];
            float n0 = (a0[i] - mu0) * rs0 * g + b;
            float n1 = (a1[i] - mu1) * rs1 * g + b;
            op[i] = 0.5f * (n0 + n1);
        }
    }
}

extern "C" void kernel_launch(void* const* d_in, const int* in_sizes, int n_in,
                              void* d_out, int out_size, void* d_ws, size_t ws_size,
                              hipStream_t stream) {
    const float* voxel = (const float*)d_in[0];
    const float* cnnf  = (const float*)d_in[1];
    const float* w1    = (const float*)d_in[2];
    const float* b1    = (const float*)d_in[3];
    const float* w2    = (const float*)d_in[4];
    const float* b2    = (const float*)d_in[5];
    const float* gamma = (const float*)d_in[6];
    const float* beta  = (const float*)d_in[7];
    float* out = (float*)d_out;

    unsigned short* W1b = (unsigned short*)d_ws;                       // 368*128*2 = 94208 B
    unsigned short* W2b = (unsigned short*)((char*)d_ws + 94208);      // 128*128*2 = 32768 B

    int nloc = in_sizes[0] / DD;   // B*N = 131072
    prep_weights<<<64, 256, 0, stream>>>(w1, w2, W1b, W2b);
    fused_attn<<<nloc / 32, 256, 0, stream>>>(voxel, cnnf, b1, b2, gamma, beta, W1b, W2b, out);
}

// Round 2
// 130.037 us; speedup vs baseline: 1.0823x; 1.0823x over previous
//
#include <hip/hip_runtime.h>
#include <hip/hip_bf16.h>
#include <stdint.h>

#define DD 120
#define HH 8
#define HD 15
#define KP 128         // K padded to 128
#define N1 360         // 3*D
#define NT1 23         // qkv n-tiles (368/16)
#define NT2 8          // out-proj n-tiles (128/16)
#define LN_EPS 1e-5f

#define TOK 32         // tokens per WG (16 locations)
#define QSTRIDE 384    // qkv row stride in shorts ([3][8][16])
#define YSTRIDE 124    // ylds row stride in floats

typedef __attribute__((ext_vector_type(8))) short bf16x8;
typedef __attribute__((ext_vector_type(4))) float f32x4;

__device__ __forceinline__ unsigned short f2bf(float f) {
    union { float f; unsigned u; } v; v.f = f;
    unsigned u = v.u + 0x7FFFu + ((v.u >> 16) & 1u);   // RNE
    return (unsigned short)(u >> 16);
}
__device__ __forceinline__ float bf2f(unsigned short h) {
    union { unsigned u; float f; } v; v.u = ((unsigned)h) << 16;
    return v.f;
}

// ---- prep: pack weights as per-tile MFMA B-fragments, bf16, in ws ----
// W1bp: [23 tiles][4 kk][64 lane][8 e]  from in_proj_w (k packed 0..119)
// W2bp: [8 tiles][4 kk][64 lane][8 e]   from out_w with HEAD-PADDED k:
//       kpad = h*16+i maps to k = h*15+i (i<15), pad rows = 0.
__global__ void prep_weights(const float* __restrict__ w1, const float* __restrict__ w2,
                             unsigned short* __restrict__ W1bp, unsigned short* __restrict__ W2bp) {
    int idx = blockIdx.x * blockDim.x + threadIdx.x;
    int stride = gridDim.x * blockDim.x;
    for (int p = idx; p < NT1 * 4 * 64 * 8; p += stride) {
        int e = p & 7, lane = (p >> 3) & 63, kk = (p >> 9) & 3, t = p >> 11;
        int n = t * 16 + (lane & 15);
        int k = kk * 32 + (lane >> 4) * 8 + e;
        unsigned short v = 0;
        if (n < N1 && k < DD) v = f2bf(w1[n * DD + k]);
        W1bp[p] = v;
    }
    for (int p = idx; p < NT2 * 4 * 64 * 8; p += stride) {
        int e = p & 7, lane = (p >> 3) & 63, kk = (p >> 9) & 3, t = p >> 11;
        int n = t * 16 + (lane & 15);
        int kpad = kk * 32 + (lane >> 4) * 8 + e;
        int h = kpad >> 4, i = kpad & 15;
        unsigned short v = 0;
        if (n < DD && i < HD) v = f2bf(w2[n * DD + h * HD + i]);
        W2bp[p] = v;
    }
}

// ---- fused kernel: 16 locations (32 tokens) per workgroup of 256 threads ----
__global__ __launch_bounds__(256) void fused_attn(
    const float* __restrict__ voxel, const float* __restrict__ cnnf,
    const float* __restrict__ in_b, const float* __restrict__ out_b,
    const float* __restrict__ gamma, const float* __restrict__ beta,
    const unsigned short* __restrict__ W1bp, const unsigned short* __restrict__ W2bp,
    float* __restrict__ out)
{
    // LDS: xo  = [32][128] bf16, XOR-swizzled 16B chunks (x, later o)   8192 B
    //      qkv = [32][384] bf16 ([3 part][8 head][16]), swizzled       24576 B
    //      ylds = [32][124] f32 (overlays qkv, phases 4-5)             15872 B
    __shared__ __align__(16) char smem[8192 + 24576];
    unsigned short* xo = (unsigned short*)smem;
    unsigned short* qkv = (unsigned short*)(smem + 8192);
    float* ylds = (float*)(smem + 8192);

    const int tid = threadIdx.x;
    const int loc0 = blockIdx.x * (TOK / 2);

    // ---------- phase 1: stage x -> bf16 swizzled LDS ----------
    // i = a*480 + l*30 + c4 : array a, location l, float4-chunk c4
    for (int i = tid; i < 2 * 16 * 30; i += 256) {
        int a = i / 480, rem = i % 480;
        int l = rem / 30, c4 = rem % 30;
        const float* src = (a ? cnnf : voxel) + (size_t)(loc0 + l) * DD + c4 * 4;
        float4 f = *(const float4*)src;
        ushort4 hv;
        hv.x = f2bf(f.x); hv.y = f2bf(f.y); hv.z = f2bf(f.z); hv.w = f2bf(f.w);
        int r = l * 2 + a;
        int c8 = c4 >> 1, sub = (c4 & 1) * 8;
        *(ushort4*)((char*)xo + r * 256 + ((c8 ^ (r & 7)) << 4) + sub) = hv;
    }
    if (tid < TOK) { // zero K-pad chunk (cols 120..127)
        int r = tid;
        *(uint4*)((char*)xo + r * 256 + ((15 ^ (r & 7)) << 4)) = make_uint4(0, 0, 0, 0);
    }
    __syncthreads();

    const int wave = tid >> 6, lane = tid & 63;
    const int lrow = lane & 15;       // n within tile / A-row
    const int lk = lane >> 4;         // k-slice 0..3

    // ---------- phase 2: QKV GEMM -> head-padded swizzled qkv ----------
    {
        bf16x8 afrag[2][4];
        #pragma unroll
        for (int m = 0; m < 2; ++m) {
            int r = m * 16 + lrow;
            #pragma unroll
            for (int kk = 0; kk < 4; ++kk) {
                int chunk = kk * 4 + lk;
                afrag[m][kk] = *(const bf16x8*)((const char*)xo + r * 256 + ((chunk ^ (r & 7)) << 4));
            }
        }
        for (int t = wave; t < NT1; t += 4) {
            int n = t * 16 + lrow;
            bf16x8 bfrag[4];
            #pragma unroll
            for (int kk = 0; kk < 4; ++kk)
                bfrag[kk] = *(const bf16x8*)(W1bp + ((size_t)((t * 4 + kk) * 64 + lane)) * 8);
            bool valid = (n < N1);
            float bias = valid ? in_b[n] : 0.f;
            int pos = 0;
            if (valid) {
                int part = n / DD, rem = n % DD;
                int h = rem / HD, ii = rem % HD;
                pos = part * 128 + h * 16 + ii;
            }
            int chunk = pos >> 3, sub = (pos & 7) * 2;
            #pragma unroll
            for (int m = 0; m < 2; ++m) {
                f32x4 acc = {0.f, 0.f, 0.f, 0.f};
                #pragma unroll
                for (int kk = 0; kk < 4; ++kk)
                    acc = __builtin_amdgcn_mfma_f32_16x16x32_bf16(afrag[m][kk], bfrag[kk], acc, 0, 0, 0);
                if (valid) {
                    #pragma unroll
                    for (int j = 0; j < 4; ++j) {
                        int row = m * 16 + lk * 4 + j;
                        *(unsigned short*)((char*)qkv + row * 768 + ((chunk ^ (row & 7)) << 4) + sub)
                            = f2bf(acc[j] + bias);
                    }
                }
            }
        }
    }
    __syncthreads();

    // ---------- phase 3: tiny attention, 2 threads per (location, head) ----------
    {
        int locl = tid >> 4;          // 0..15
        int h = (tid >> 1) & 7;
        int qr = tid & 1;
        int r0 = locl * 2, r1 = r0 + 1, rq = r0 + qr;
        auto rd = [&](int row, int chunk) -> bf16x8 {
            return *(const bf16x8*)((const char*)qkv + row * 768 + ((chunk ^ (row & 7)) << 4));
        };
        bf16x8 qa = rd(rq, h * 2),      qb = rd(rq, h * 2 + 1);
        bf16x8 k0a = rd(r0, 16 + h * 2), k0b = rd(r0, 16 + h * 2 + 1);
        bf16x8 k1a = rd(r1, 16 + h * 2), k1b = rd(r1, 16 + h * 2 + 1);
        bf16x8 v0a = rd(r0, 32 + h * 2), v0b = rd(r0, 32 + h * 2 + 1);
        bf16x8 v1a = rd(r1, 32 + h * 2), v1b = rd(r1, 32 + h * 2 + 1);
        float s0 = 0.f, s1 = 0.f;
        #pragma unroll
        for (int i = 0; i < 8; ++i) {
            float q = bf2f((unsigned short)qa[i]);
            s0 += q * bf2f((unsigned short)k0a[i]);
            s1 += q * bf2f((unsigned short)k1a[i]);
        }
        #pragma unroll
        for (int i = 0; i < 7; ++i) {
            float q = bf2f((unsigned short)qb[i]);
            s0 += q * bf2f((unsigned short)k0b[i]);
            s1 += q * bf2f((unsigned short)k1b[i]);
        }
        const float scale = 0.25819888974716112567f; // 1/sqrt(15)
        s0 *= scale; s1 *= scale;
        float mx = fmaxf(s0, s1);
        float e0 = __expf(s0 - mx), e1 = __expf(s1 - mx);
        float dinv = 1.f / (e0 + e1);
        float p0 = e0 * dinv, p1 = e1 * dinv;
        bf16x8 oa, ob;
        #pragma unroll
        for (int i = 0; i < 8; ++i)
            oa[i] = (short)f2bf(p0 * bf2f((unsigned short)v0a[i]) + p1 * bf2f((unsigned short)v1a[i]));
        #pragma unroll
        for (int i = 0; i < 7; ++i)
            ob[i] = (short)f2bf(p0 * bf2f((unsigned short)v0b[i]) + p1 * bf2f((unsigned short)v1b[i]));
        ob[7] = 0;  // pad lane MUST be finite (W2bp pad row is 0, avoid NaN*0)
        *(bf16x8*)((char*)xo + rq * 256 + (((h * 2)     ^ (rq & 7)) << 4)) = oa;
        *(bf16x8*)((char*)xo + rq * 256 + (((h * 2 + 1) ^ (rq & 7)) << 4)) = ob;
    }
    __syncthreads();

    // ---------- phase 4: out projection (A = o, head-padded k; B = W2bp) ----------
    {
        bf16x8 ofrag[2][4];
        #pragma unroll
        for (int m = 0; m < 2; ++m) {
            int r = m * 16 + lrow;
            #pragma unroll
            for (int kk = 0; kk < 4; ++kk) {
                int chunk = kk * 4 + lk;
                ofrag[m][kk] = *(const bf16x8*)((const char*)xo + r * 256 + ((chunk ^ (r & 7)) << 4));
            }
        }
        #pragma unroll
        for (int tt = 0; tt < 2; ++tt) {
            int t = wave + tt * 4;
            int n = t * 16 + lrow;   // 0..127
            bf16x8 bfrag[4];
            #pragma unroll
            for (int kk = 0; kk < 4; ++kk)
                bfrag[kk] = *(const bf16x8*)(W2bp + ((size_t)((t * 4 + kk) * 64 + lane)) * 8);
            bool valid = (n < DD);
            float bias = valid ? out_b[n] : 0.f;
            #pragma unroll
            for (int m = 0; m < 2; ++m) {
                f32x4 acc = {0.f, 0.f, 0.f, 0.f};
                #pragma unroll
                for (int kk = 0; kk < 4; ++kk)
                    acc = __builtin_amdgcn_mfma_f32_16x16x32_bf16(ofrag[m][kk], bfrag[kk], acc, 0, 0, 0);
                if (valid) {
                    #pragma unroll
                    for (int j = 0; j < 4; ++j) {
                        int row = m * 16 + lk * 4 + j;
                        ylds[row * YSTRIDE + n] = acc[j] + bias;
                    }
                }
            }
        }
    }
    __syncthreads();

    // ---------- phase 5: LayerNorm + mean-pool, 16 threads per location ----------
    {
        int locl = tid >> 4;          // 0..15
        int s = tid & 15;
        int row = locl * 2 + (s & 1);
        int c0 = (s >> 1) * HD;       // 8 col-groups of 15
        const float* y = ylds + row * YSTRIDE + c0;
        float a[HD];
        float sum = 0.f, sq = 0.f;
        #pragma unroll
        for (int i = 0; i < HD; ++i) {
            a[i] = y[i];
            sum += a[i]; sq += a[i] * a[i];
        }
        #pragma unroll
        for (int w = 2; w < 16; w <<= 1) {   // reduce over the 8 same-row threads
            sum += __shfl_xor(sum, w);
            sq  += __shfl_xor(sq, w);
        }
        const float inv = 1.f / 120.f;
        float mu = sum * inv;
        float var = sq * inv - mu * mu;
        float rs = rsqrtf(var + LN_EPS);
        float* op = out + (size_t)(loc0 + locl) * DD + c0;
        #pragma unroll
        for (int i = 0; i < HD; ++i) {
            int d = c0 + i;
            float nrm = (a[i] - mu) * rs * gamma[d] + beta[d];
            float other = __shfl_xor(nrm, 1);  // partner row's normalized value
            if ((s & 1) == 0) op[i] = 0.5f * (nrm + other);
        }
    }
}

extern "C" void kernel_launch(void* const* d_in, const int* in_sizes, int n_in,
                              void* d_out, int out_size, void* d_ws, size_t ws_size,
                              hipStream_t stream) {
    const float* voxel = (const float*)d_in[0];
    const float* cnnf  = (const float*)d_in[1];
    const float* w1    = (const float*)d_in[2];
    const float* b1    = (const float*)d_in[3];
    const float* w2    = (const float*)d_in[4];
    const float* b2    = (const float*)d_in[5];
    const float* gamma = (const float*)d_in[6];
    const float* beta  = (const float*)d_in[7];
    float* out = (float*)d_out;

    unsigned short* W1bp = (unsigned short*)d_ws;                        // 23*4*64*8*2 = 94208 B
    unsigned short* W2bp = (unsigned short*)((char*)d_ws + 94208);       // 8*4*64*8*2  = 32768 B

    int nloc = in_sizes[0] / DD;   // B*N = 131072
    prep_weights<<<64, 256, 0, stream>>>(w1, w2, W1bp, W2bp);
    fused_attn<<<nloc / 16, 256, 0, stream>>>(voxel, cnnf, b1, b2, gamma, beta, W1bp, W2bp, out);
}

// Round 3
// 116.492 us; speedup vs baseline: 1.2081x; 1.1163x over previous
//
#include <hip/hip_runtime.h>
#include <hip/hip_bf16.h>
#include <stdint.h>

#define DD 120
#define HH 8
#define HD 15
#define N1 360
#define NT1 24         // head-padded qkv n-tiles (384/16)
#define NT2 8          // out-proj n-tiles (128/16)
#define LN_EPS 1e-5f

typedef __attribute__((ext_vector_type(8))) short bf16x8;
typedef __attribute__((ext_vector_type(4))) float f32x4;

__device__ __forceinline__ unsigned short f2bf(float f) {
    return __bfloat16_as_ushort(__float2bfloat16(f));   // native RNE cvt (pairs fuse to cvt_pk)
}
__device__ __forceinline__ float bf2f(unsigned short h) {
    union { unsigned u; float f; } v; v.u = ((unsigned)h) << 16;
    return v.f;
}

// ---- prep: pack weights as MFMA operand-fragments (bf16) + padded biases in ws ----
// W1bp: [24 t][4 kk][64 lane][8 e]; padded channel pos = t*16+(lane&15) = part*128+h*16+i
// W2bp: [8 t][4 kk][64 lane][8 e];  n = t*16+(lane&15) plain (>=120 -> 0), k head-padded
// b1p[384] head-padded in_proj bias; b2p[128] padded out bias
__global__ void prep_weights(const float* __restrict__ w1, const float* __restrict__ w2,
                             const float* __restrict__ b1, const float* __restrict__ b2,
                             unsigned short* __restrict__ W1bp, unsigned short* __restrict__ W2bp,
                             float* __restrict__ b1p, float* __restrict__ b2p) {
    int idx = blockIdx.x * blockDim.x + threadIdx.x;
    int stride = gridDim.x * blockDim.x;
    for (int p = idx; p < NT1 * 4 * 64 * 8; p += stride) {
        int e = p & 7, lane = (p >> 3) & 63, kk = (p >> 9) & 3, t = p >> 11;
        int pos = t * 16 + (lane & 15);
        int part = pos >> 7, rem = pos & 127, h = rem >> 4, i = rem & 15;
        int k = kk * 32 + (lane >> 4) * 8 + e;
        unsigned short v = 0;
        if (i < HD && k < DD) v = f2bf(w1[(part * DD + h * HD + i) * DD + k]);
        W1bp[p] = v;
    }
    for (int p = idx; p < NT2 * 4 * 64 * 8; p += stride) {
        int e = p & 7, lane = (p >> 3) & 63, kk = (p >> 9) & 3, t = p >> 11;
        int n = t * 16 + (lane & 15);
        int kpad = kk * 32 + (lane >> 4) * 8 + e;
        int h = kpad >> 4, i = kpad & 15;
        unsigned short v = 0;
        if (n < DD && i < HD) v = f2bf(w2[n * DD + h * HD + i]);
        W2bp[p] = v;
    }
    for (int p = idx; p < 384; p += stride) {
        int part = p >> 7, rem = p & 127, h = rem >> 4, i = rem & 15;
        b1p[p] = (i < HD) ? b1[part * DD + h * HD + i] : 0.f;
    }
    for (int p = idx; p < 128; p += stride)
        b2p[p] = (p < DD) ? b2[p] : 0.f;
}

// ---- fused kernel: 32 locations (64 tokens), 512 threads / 8 waves per WG ----
__global__ __launch_bounds__(512, 4) void fused_attn(
    const float* __restrict__ voxel, const float* __restrict__ cnnf,
    const float* __restrict__ gamma, const float* __restrict__ beta,
    const unsigned short* __restrict__ W1bp, const unsigned short* __restrict__ W2bp,
    const float* __restrict__ b1p, const float* __restrict__ b2p,
    float* __restrict__ out)
{
    // xo  : [64][128] bf16, 16B-chunk XOR-swizzled (x, later o)   16384 B
    // qkv : [64][384] bf16 head-padded [3][8][16], swizzled       49152 B
    // ylds: [64][128] f32 swizzled (overlays qkv)                 32768 B
    __shared__ __align__(16) char smem[16384 + 49152];
    unsigned short* xo = (unsigned short*)smem;
    unsigned short* qkv = (unsigned short*)(smem + 16384);
    float* ylds = (float*)(smem + 16384);

    const int tid = threadIdx.x;
    const int wave = tid >> 6, lane = tid & 63;
    const int lrow = lane & 15, lk = lane >> 4;
    const int loc0 = blockIdx.x * 32;
    const int tt = wave & 3;        // token-tile 0..3
    const int th = wave >> 2;       // n-tile interleave half 0/1

    // prefetch first W1 A-frags + bias (completes during phase 1)
    bf16x8 aN[4]; f32x4 bN;
    {
        int t = th;
        #pragma unroll
        for (int kk = 0; kk < 4; ++kk)
            aN[kk] = *(const bf16x8*)(W1bp + ((size_t)((t * 4 + kk) * 64 + lane)) * 8);
        bN = *(const f32x4*)(b1p + t * 16 + lk * 4);
    }

    // ---------- phase 1: stage x -> bf16 swizzled LDS ----------
    for (int i = tid; i < 2 * 32 * 30; i += 512) {
        int a = i / 960, rem = i % 960;
        int l = rem / 30, c4 = rem % 30;
        const float* src = (a ? cnnf : voxel) + (size_t)(loc0 + l) * DD + c4 * 4;
        float4 f = *(const float4*)src;
        ushort4 hv;
        hv.x = f2bf(f.x); hv.y = f2bf(f.y); hv.z = f2bf(f.z); hv.w = f2bf(f.w);
        int r = l * 2 + a;
        int c8 = c4 >> 1, sub = (c4 & 1) * 8;
        *(ushort4*)((char*)xo + r * 256 + ((c8 ^ (r & 7)) << 4) + sub) = hv;
    }
    if (tid < 64) { // zero K-pad chunk (cols 120..127)
        int r = tid;
        *(uint4*)((char*)xo + r * 256 + ((15 ^ (r & 7)) << 4)) = make_uint4(0, 0, 0, 0);
    }
    __syncthreads();

    // ---------- phase 2: QKV GEMM, A=W1 (channels), B=x (tokens) ----------
    {
        bf16x8 bfrag[4];
        int r = tt * 16 + lrow;
        #pragma unroll
        for (int kk = 0; kk < 4; ++kk) {
            int chunk = kk * 4 + lk;
            bfrag[kk] = *(const bf16x8*)((const char*)xo + r * 256 + ((chunk ^ (r & 7)) << 4));
        }
        const int tok = r;
        const int rsw = tok & 7;
        for (int jj = 0; jj < 12; ++jj) {
            int t = th + 2 * jj;
            bf16x8 aC[4]; f32x4 bC = bN;
            #pragma unroll
            for (int kk = 0; kk < 4; ++kk) aC[kk] = aN[kk];
            if (jj < 11) {
                int tn = th + 2 * (jj + 1);
                #pragma unroll
                for (int kk = 0; kk < 4; ++kk)
                    aN[kk] = *(const bf16x8*)(W1bp + ((size_t)((tn * 4 + kk) * 64 + lane)) * 8);
                bN = *(const f32x4*)(b1p + tn * 16 + lk * 4);
            }
            f32x4 acc = {0.f, 0.f, 0.f, 0.f};
            #pragma unroll
            for (int kk = 0; kk < 4; ++kk)
                acc = __builtin_amdgcn_mfma_f32_16x16x32_bf16(aC[kk], bfrag[kk], acc, 0, 0, 0);
            int p0 = t * 16 + lk * 4;       // 4 consecutive padded channels of token tok
            ushort4 hv;
            hv.x = f2bf(acc[0] + bC[0]); hv.y = f2bf(acc[1] + bC[1]);
            hv.z = f2bf(acc[2] + bC[2]); hv.w = f2bf(acc[3] + bC[3]);
            int chunk = p0 >> 3, sub = (p0 & 7) * 2;
            *(ushort4*)((char*)qkv + tok * 768 + ((chunk ^ rsw) << 4) + sub) = hv;
        }
    }
    // prefetch first W2 A-frags + bias (hide L2 latency under attention)
    bf16x8 a2N[4]; f32x4 b2N;
    {
        int t = th;
        #pragma unroll
        for (int kk = 0; kk < 4; ++kk)
            a2N[kk] = *(const bf16x8*)(W2bp + ((size_t)((t * 4 + kk) * 64 + lane)) * 8);
        b2N = *(const f32x4*)(b2p + t * 16 + lk * 4);
    }
    __syncthreads();

    // ---------- phase 3: tiny attention, thread = (loc, head, qrow) ----------
    {
        int locl = tid >> 4;
        int h = (tid >> 1) & 7;
        int qr = tid & 1;
        int r0 = locl * 2, r1 = r0 + 1, rq = r0 + qr;
        auto rd = [&](int row, int chunk) -> bf16x8 {
            return *(const bf16x8*)((const char*)qkv + row * 768 + ((chunk ^ (row & 7)) << 4));
        };
        bf16x8 qa = rd(rq, h * 2),       qb = rd(rq, h * 2 + 1);
        bf16x8 k0a = rd(r0, 16 + h * 2), k0b = rd(r0, 16 + h * 2 + 1);
        bf16x8 k1a = rd(r1, 16 + h * 2), k1b = rd(r1, 16 + h * 2 + 1);
        bf16x8 v0a = rd(r0, 32 + h * 2), v0b = rd(r0, 32 + h * 2 + 1);
        bf16x8 v1a = rd(r1, 32 + h * 2), v1b = rd(r1, 32 + h * 2 + 1);
        float s0 = 0.f, s1 = 0.f;
        #pragma unroll
        for (int i = 0; i < 8; ++i) {
            float q = bf2f((unsigned short)qa[i]);
            s0 += q * bf2f((unsigned short)k0a[i]);
            s1 += q * bf2f((unsigned short)k1a[i]);
        }
        #pragma unroll
        for (int i = 0; i < 7; ++i) {
            float q = bf2f((unsigned short)qb[i]);
            s0 += q * bf2f((unsigned short)k0b[i]);
            s1 += q * bf2f((unsigned short)k1b[i]);
        }
        const float scale = 0.25819888974716112567f; // 1/sqrt(15)
        s0 *= scale; s1 *= scale;
        float mx = fmaxf(s0, s1);
        float e0 = __expf(s0 - mx), e1 = __expf(s1 - mx);
        float dinv = 1.f / (e0 + e1);
        float p0 = e0 * dinv, p1 = e1 * dinv;
        bf16x8 oa, ob;
        #pragma unroll
        for (int i = 0; i < 8; ++i)
            oa[i] = (short)f2bf(p0 * bf2f((unsigned short)v0a[i]) + p1 * bf2f((unsigned short)v1a[i]));
        #pragma unroll
        for (int i = 0; i < 7; ++i)
            ob[i] = (short)f2bf(p0 * bf2f((unsigned short)v0b[i]) + p1 * bf2f((unsigned short)v1b[i]));
        ob[7] = 0;  // pad lane must be finite
        *(bf16x8*)((char*)xo + rq * 256 + (((h * 2)     ^ (rq & 7)) << 4)) = oa;
        *(bf16x8*)((char*)xo + rq * 256 + (((h * 2 + 1) ^ (rq & 7)) << 4)) = ob;
    }
    __syncthreads();

    // ---------- phase 4: out projection, A=W2 (channels), B=o (tokens) ----------
    {
        bf16x8 bfrag[4];
        int r = tt * 16 + lrow;
        #pragma unroll
        for (int kk = 0; kk < 4; ++kk) {
            int chunk = kk * 4 + lk;
            bfrag[kk] = *(const bf16x8*)((const char*)xo + r * 256 + ((chunk ^ (r & 7)) << 4));
        }
        const int tok = r;
        const int rsw = tok & 7;
        for (int jj = 0; jj < 4; ++jj) {
            int t = th + 2 * jj;
            bf16x8 aC[4]; f32x4 bC = b2N;
            #pragma unroll
            for (int kk = 0; kk < 4; ++kk) aC[kk] = a2N[kk];
            if (jj < 3) {
                int tn = th + 2 * (jj + 1);
                #pragma unroll
                for (int kk = 0; kk < 4; ++kk)
                    a2N[kk] = *(const bf16x8*)(W2bp + ((size_t)((tn * 4 + kk) * 64 + lane)) * 8);
                b2N = *(const f32x4*)(b2p + tn * 16 + lk * 4);
            }
            f32x4 acc = {0.f, 0.f, 0.f, 0.f};
            #pragma unroll
            for (int kk = 0; kk < 4; ++kk)
                acc = __builtin_amdgcn_mfma_f32_16x16x32_bf16(aC[kk], bfrag[kk], acc, 0, 0, 0);
            f32x4 vv;
            vv[0] = acc[0] + bC[0]; vv[1] = acc[1] + bC[1];
            vv[2] = acc[2] + bC[2]; vv[3] = acc[3] + bC[3];
            int c = t * 4 + lk;                 // 16B chunk index 0..31
            *(f32x4*)((char*)ylds + tok * 512 + ((c ^ rsw) << 4)) = vv;
        }
    }
    __syncthreads();

    // ---------- phase 5: LayerNorm + mean-pool, 16 threads per location ----------
    {
        int locl = tid >> 4;
        int s = tid & 15;
        int row = locl * 2 + (s & 1);
        int g = s >> 1;                 // 0..7
        float a[16];
        float sum = 0.f, sq = 0.f;
        #pragma unroll
        for (int q = 0; q < 4; ++q) {
            int c = g + 8 * q;
            f32x4 v = {0.f, 0.f, 0.f, 0.f};
            if (c < 30)
                v = *(const f32x4*)((const char*)ylds + row * 512 + ((c ^ (row & 7)) << 4));
            #pragma unroll
            for (int j = 0; j < 4; ++j) {
                a[q * 4 + j] = v[j];
                sum += v[j]; sq += v[j] * v[j];
            }
        }
        #pragma unroll
        for (int w = 2; w < 16; w <<= 1) {   // reduce over the 8 same-row threads
            sum += __shfl_xor(sum, w);
            sq  += __shfl_xor(sq, w);
        }
        const float inv = 1.f / 120.f;
        float mu = sum * inv;
        float var = sq * inv - mu * mu;
        float rs = rsqrtf(var + LN_EPS);
        float* op = out + (size_t)(loc0 + locl) * DD;
        #pragma unroll
        for (int q = 0; q < 4; ++q) {
            int c = g + 8 * q;
            if (c < 30) {
                f32x4 gm = *(const f32x4*)(gamma + c * 4);
                f32x4 bt = *(const f32x4*)(beta + c * 4);
                float4 o4;
                float n0 = (a[q * 4 + 0] - mu) * rs * gm[0] + bt[0];
                float n1 = (a[q * 4 + 1] - mu) * rs * gm[1] + bt[1];
                float n2 = (a[q * 4 + 2] - mu) * rs * gm[2] + bt[2];
                float n3 = (a[q * 4 + 3] - mu) * rs * gm[3] + bt[3];
                o4.x = 0.5f * (n0 + __shfl_xor(n0, 1));
                o4.y = 0.5f * (n1 + __shfl_xor(n1, 1));
                o4.z = 0.5f * (n2 + __shfl_xor(n2, 1));
                o4.w = 0.5f * (n3 + __shfl_xor(n3, 1));
                if ((s & 1) == 0) *(float4*)(op + c * 4) = o4;
            }
        }
    }
}

extern "C" void kernel_launch(void* const* d_in, const int* in_sizes, int n_in,
                              void* d_out, int out_size, void* d_ws, size_t ws_size,
                              hipStream_t stream) {
    const float* voxel = (const float*)d_in[0];
    const float* cnnf  = (const float*)d_in[1];
    const float* w1    = (const float*)d_in[2];
    const float* b1    = (const float*)d_in[3];
    const float* w2    = (const float*)d_in[4];
    const float* b2    = (const float*)d_in[5];
    const float* gamma = (const float*)d_in[6];
    const float* beta  = (const float*)d_in[7];
    float* out = (float*)d_out;

    unsigned short* W1bp = (unsigned short*)d_ws;                         // 98304 B
    unsigned short* W2bp = (unsigned short*)((char*)d_ws + 98304);        // 32768 B
    float* b1p = (float*)((char*)d_ws + 131072);                          // 1536 B
    float* b2p = (float*)((char*)d_ws + 132608);                          // 512 B

    int nloc = in_sizes[0] / DD;   // 131072
    prep_weights<<<128, 256, 0, stream>>>(w1, w2, b1, b2, W1bp, W2bp, b1p, b2p);
    fused_attn<<<nloc / 32, 512, 0, stream>>>(voxel, cnnf, gamma, beta, W1bp, W2bp, b1p, b2p, out);
}

// Round 4
// 108.805 us; speedup vs baseline: 1.2935x; 1.0706x over previous
//
#include <hip/hip_runtime.h>
#include <hip/hip_bf16.h>
#include <stdint.h>

#define DD 120
#define HD 15
#define LN_EPS 1e-5f

typedef __attribute__((ext_vector_type(8))) short bf16x8;
typedef __attribute__((ext_vector_type(4))) float f32x4;

__device__ __forceinline__ unsigned short f2bf(float f) {
    return __bfloat16_as_ushort(__float2bfloat16(f));
}
__device__ __forceinline__ float bf2f(unsigned short h) {
    union { unsigned u; float f; } v; v.u = ((unsigned)h) << 16;
    return v.f;
}

// ---- prep: pack weights as MFMA A-fragments with bias folded into k=120 ----
// W1bp: [24 t][4 kk][64 lane][8 e]; A-row n = padded qkv channel t*16+(lane&15)
//       k<120: weight; k==120: bias (i<15) / 1.0 marker for V-head0-pad (part==2,h==0,i==15)
// W2bp: [8 t][4 kk][64 lane][8 e]; A-row n = out channel; k = head-padded o-channel;
//       kpad==15 carries out_b (fed by O[15]==1.0)
__global__ void prep_weights(const float* __restrict__ w1, const float* __restrict__ w2,
                             const float* __restrict__ b1, const float* __restrict__ b2,
                             unsigned short* __restrict__ W1bp, unsigned short* __restrict__ W2bp) {
    int idx = blockIdx.x * blockDim.x + threadIdx.x;
    int stride = gridDim.x * blockDim.x;
    for (int p = idx; p < 24 * 4 * 64 * 8; p += stride) {
        int e = p & 7, lane = (p >> 3) & 63, kk = (p >> 9) & 3, t = p >> 11;
        int pos = t * 16 + (lane & 15);
        int part = pos >> 7, rem = pos & 127, h = rem >> 4, i = rem & 15;
        int k = kk * 32 + (lane >> 4) * 8 + e;
        float v = 0.f;
        if (k < DD)        { if (i < HD) v = w1[(part * DD + h * HD + i) * DD + k]; }
        else if (k == DD)  { if (i < HD) v = b1[part * DD + h * HD + i];
                             else if (part == 2 && h == 0) v = 1.0f; }
        W1bp[p] = f2bf(v);
    }
    for (int p = idx; p < 8 * 4 * 64 * 8; p += stride) {
        int e = p & 7, lane = (p >> 3) & 63, kk = (p >> 9) & 3, t = p >> 11;
        int n = t * 16 + (lane & 15);
        int kpad = kk * 32 + (lane >> 4) * 8 + e;
        int i = kpad & 15, h = kpad >> 4;
        float v = 0.f;
        if (n < DD) {
            if (i < HD) v = w2[n * DD + h * HD + i];
            else if (kpad == 15) v = b2[n];
        }
        W2bp[p] = f2bf(v);
    }
}

// ---- fused: 16 locations (32 tokens) per 256-thread WG; QKV+attn in registers ----
__global__ __launch_bounds__(256, 4) void fused_attn(
    const float* __restrict__ voxel, const float* __restrict__ cnnf,
    const float* __restrict__ gamma, const float* __restrict__ beta,
    const unsigned short* __restrict__ W1bp, const unsigned short* __restrict__ W2bp,
    float* __restrict__ out)
{
    // obuf: [32 tok][128 pos] bf16, 16B-chunk XOR-swizzled   8192 B
    // ybuf: [32 tok][128 n]   bf16, swizzled                 8192 B
    __shared__ __align__(16) char smem[8192 + 8192];
    unsigned short* obuf = (unsigned short*)smem;
    unsigned short* ybuf = (unsigned short*)(smem + 8192);

    const int tid = threadIdx.x;
    const int wave = tid >> 6, lane = tid & 63;
    const int lrow = lane & 15, lk = lane >> 4;
    const int tt = wave >> 1, th = wave & 1;     // token-tile, head-parity
    const int tokl = tt * 16 + lrow;             // local token 0..31
    const int gtok = blockIdx.x * 32 + tokl;     // global token
    const int r7 = tokl & 7;

    // ---- x B-frags direct from global (8 consecutive k per lane) ----
    bf16x8 bfrag[4];
    {
        const float* src = ((gtok & 1) ? cnnf : voxel) + (size_t)(gtok >> 1) * DD;
        #pragma unroll
        for (int kk = 0; kk < 4; ++kk) {
            bf16x8 hv;
            if (kk == 3 && lk == 3) {
                hv = (bf16x8){(short)0x3F80, 0, 0, 0, 0, 0, 0, 0};  // x[120]=1.0 bias channel
            } else {
                const float* p = src + kk * 32 + lk * 8;
                float4 f0 = *(const float4*)p;
                float4 f1 = *(const float4*)(p + 4);
                hv[0] = (short)f2bf(f0.x); hv[1] = (short)f2bf(f0.y);
                hv[2] = (short)f2bf(f0.z); hv[3] = (short)f2bf(f0.w);
                hv[4] = (short)f2bf(f1.x); hv[5] = (short)f2bf(f1.y);
                hv[6] = (short)f2bf(f1.z); hv[7] = (short)f2bf(f1.w);
            }
            bfrag[kk] = hv;
        }
    }

    // ---- QKV GEMM: stream 12 W1 tiles (t = th+2*jj), C stays in registers ----
    f32x4 Qc[4], Kc[4], Vc[4];
    {
        bf16x8 aN[4];
        #pragma unroll
        for (int kk = 0; kk < 4; ++kk)
            aN[kk] = *(const bf16x8*)(W1bp + ((size_t)((th * 4 + kk) * 64 + lane)) * 8);
        #pragma unroll
        for (int jj = 0; jj < 12; ++jj) {
            bf16x8 aC[4];
            #pragma unroll
            for (int kk = 0; kk < 4; ++kk) aC[kk] = aN[kk];
            if (jj < 11) {
                int tn = th + 2 * (jj + 1);
                #pragma unroll
                for (int kk = 0; kk < 4; ++kk)
                    aN[kk] = *(const bf16x8*)(W1bp + ((size_t)((tn * 4 + kk) * 64 + lane)) * 8);
            }
            f32x4 acc = {0.f, 0.f, 0.f, 0.f};
            #pragma unroll
            for (int kk = 0; kk < 4; ++kk)
                acc = __builtin_amdgcn_mfma_f32_16x16x32_bf16(aC[kk], bfrag[kk], acc, 0, 0, 0);
            if (jj < 4) Qc[jj] = acc;
            else if (jj < 8) Kc[jj - 4] = acc;
            else Vc[jj - 8] = acc;
        }
    }

    // ---- attention fully in registers: partner token is lane^1 ----
    {
        const float scale = 0.25819888974716112567f;  // 1/sqrt(15)
        #pragma unroll
        for (int hh = 0; hh < 4; ++hh) {
            int h = th + 2 * hh;
            float kn0 = __shfl_xor(Kc[hh][0], 1), kn1 = __shfl_xor(Kc[hh][1], 1);
            float kn2 = __shfl_xor(Kc[hh][2], 1), kn3 = __shfl_xor(Kc[hh][3], 1);
            float ps = Qc[hh][0] * Kc[hh][0] + Qc[hh][1] * Kc[hh][1]
                     + Qc[hh][2] * Kc[hh][2] + Qc[hh][3] * Kc[hh][3];
            float pn = Qc[hh][0] * kn0 + Qc[hh][1] * kn1
                     + Qc[hh][2] * kn2 + Qc[hh][3] * kn3;
            ps += __shfl_xor(ps, 16); ps += __shfl_xor(ps, 32);
            pn += __shfl_xor(pn, 16); pn += __shfl_xor(pn, 32);
            float s0 = ps * scale, s1 = pn * scale;
            float m = fmaxf(s0, s1);
            float e0 = __expf(s0 - m), e1 = __expf(s1 - m);
            float r = 1.f / (e0 + e1);
            float p0 = e0 * r, p1 = e1 * r;
            float o0 = p0 * Vc[hh][0] + p1 * __shfl_xor(Vc[hh][0], 1);
            float o1 = p0 * Vc[hh][1] + p1 * __shfl_xor(Vc[hh][1], 1);
            float o2 = p0 * Vc[hh][2] + p1 * __shfl_xor(Vc[hh][2], 1);
            float o3 = p0 * Vc[hh][3] + p1 * __shfl_xor(Vc[hh][3], 1);
            // write O (pos = 16h+4lk+j) as bf16 pairs; V-head0-pad==1.0 rides along
            unsigned w0 = (unsigned)f2bf(o0) | ((unsigned)f2bf(o1) << 16);
            unsigned w1v = (unsigned)f2bf(o2) | ((unsigned)f2bf(o3) << 16);
            int chunk = 2 * h + (lk >> 1);
            *(uint2*)((char*)obuf + tokl * 256 + ((chunk ^ r7) << 4) + (lk & 1) * 8)
                = make_uint2(w0, w1v);
        }
    }
    __syncthreads();

    // ---- out projection: A=W2, B=O (from obuf); y -> ybuf bf16 ----
    {
        bf16x8 ofrag[4];
        #pragma unroll
        for (int kk = 0; kk < 4; ++kk) {
            int chunk = kk * 4 + lk;
            ofrag[kk] = *(const bf16x8*)((const char*)obuf + tokl * 256 + ((chunk ^ r7) << 4));
        }
        bf16x8 aN[4];
        #pragma unroll
        for (int kk = 0; kk < 4; ++kk)
            aN[kk] = *(const bf16x8*)(W2bp + ((size_t)((th * 4 + kk) * 64 + lane)) * 8);
        #pragma unroll
        for (int jj = 0; jj < 4; ++jj) {
            int t = th + 2 * jj;
            bf16x8 aC[4];
            #pragma unroll
            for (int kk = 0; kk < 4; ++kk) aC[kk] = aN[kk];
            if (jj < 3) {
                int tn = th + 2 * (jj + 1);
                #pragma unroll
                for (int kk = 0; kk < 4; ++kk)
                    aN[kk] = *(const bf16x8*)(W2bp + ((size_t)((tn * 4 + kk) * 64 + lane)) * 8);
            }
            f32x4 acc = {0.f, 0.f, 0.f, 0.f};
            #pragma unroll
            for (int kk = 0; kk < 4; ++kk)
                acc = __builtin_amdgcn_mfma_f32_16x16x32_bf16(aC[kk], ofrag[kk], acc, 0, 0, 0);
            // y channels n = t*16+4lk+j (pad n>=120 computes 0 naturally)
            unsigned w0 = (unsigned)f2bf(acc[0]) | ((unsigned)f2bf(acc[1]) << 16);
            unsigned w1v = (unsigned)f2bf(acc[2]) | ((unsigned)f2bf(acc[3]) << 16);
            int chunk = 2 * t + (lk >> 1);
            *(uint2*)((char*)ybuf + tokl * 256 + ((chunk ^ r7) << 4) + (lk & 1) * 8)
                = make_uint2(w0, w1v);
        }
    }
    __syncthreads();

    // ---- LayerNorm + mean-pool: 16 threads per location ----
    {
        int locl = tid >> 4;          // 0..15
        int s = tid & 15;
        int r = 2 * locl + (s & 1);   // token row
        int g = s >> 1;               // 0..7 chunk group
        int rr7 = r & 7;
        bf16x8 ya = *(const bf16x8*)((const char*)ybuf + r * 256 + ((g ^ rr7) << 4));
        bf16x8 yb = *(const bf16x8*)((const char*)ybuf + r * 256 + (((g + 8) ^ rr7) << 4));
        float a[16];
        float sum = 0.f, sq = 0.f;
        #pragma unroll
        for (int j = 0; j < 8; ++j) {
            a[j] = bf2f((unsigned short)ya[j]);
            a[8 + j] = bf2f((unsigned short)yb[j]);
            sum += a[j] + a[8 + j];
            sq += a[j] * a[j] + a[8 + j] * a[8 + j];
        }
        #pragma unroll
        for (int w = 2; w < 16; w <<= 1) {
            sum += __shfl_xor(sum, w);
            sq  += __shfl_xor(sq, w);
        }
        const float inv = 1.f / 120.f;
        float mu = sum * inv;
        float var = sq * inv - mu * mu;
        float rs = rsqrtf(var + LN_EPS);
        float* op = out + (size_t)(blockIdx.x * 16 + locl) * DD;
        // pooled = 0.5*(z0+z1)*gamma + beta  (linearity of LN affine)
        float z[16], zp[16];
        #pragma unroll
        for (int j = 0; j < 16; ++j) {
            z[j] = (a[j] - mu) * rs;
            zp[j] = __shfl_xor(z[j], 1);
        }
        if ((s & 1) == 0) {
            float4 o4;
            #pragma unroll
            for (int q = 0; q < 2; ++q) {
                int c = 8 * g + 4 * q;    // < 120 always
                f32x4 gm = *(const f32x4*)(gamma + c);
                f32x4 bt = *(const f32x4*)(beta + c);
                o4.x = 0.5f * (z[4 * q + 0] + zp[4 * q + 0]) * gm[0] + bt[0];
                o4.y = 0.5f * (z[4 * q + 1] + zp[4 * q + 1]) * gm[1] + bt[1];
                o4.z = 0.5f * (z[4 * q + 2] + zp[4 * q + 2]) * gm[2] + bt[2];
                o4.w = 0.5f * (z[4 * q + 3] + zp[4 * q + 3]) * gm[3] + bt[3];
                *(float4*)(op + c) = o4;
            }
            if (g < 7) {
                #pragma unroll
                for (int q = 0; q < 2; ++q) {
                    int c = 64 + 8 * g + 4 * q;   // < 120 when g<7
                    f32x4 gm = *(const f32x4*)(gamma + c);
                    f32x4 bt = *(const f32x4*)(beta + c);
                    o4.x = 0.5f * (z[8 + 4 * q + 0] + zp[8 + 4 * q + 0]) * gm[0] + bt[0];
                    o4.y = 0.5f * (z[8 + 4 * q + 1] + zp[8 + 4 * q + 1]) * gm[1] + bt[1];
                    o4.z = 0.5f * (z[8 + 4 * q + 2] + zp[8 + 4 * q + 2]) * gm[2] + bt[2];
                    o4.w = 0.5f * (z[8 + 4 * q + 3] + zp[8 + 4 * q + 3]) * gm[3] + bt[3];
                    *(float4*)(op + c) = o4;
                }
            }
        }
    }
}

extern "C" void kernel_launch(void* const* d_in, const int* in_sizes, int n_in,
                              void* d_out, int out_size, void* d_ws, size_t ws_size,
                              hipStream_t stream) {
    const float* voxel = (const float*)d_in[0];
    const float* cnnf  = (const float*)d_in[1];
    const float* w1    = (const float*)d_in[2];
    const float* b1    = (const float*)d_in[3];
    const float* w2    = (const float*)d_in[4];
    const float* b2    = (const float*)d_in[5];
    const float* gamma = (const float*)d_in[6];
    const float* beta  = (const float*)d_in[7];
    float* out = (float*)d_out;

    unsigned short* W1bp = (unsigned short*)d_ws;                    // 24*4*64*8*2 = 98304 B
    unsigned short* W2bp = (unsigned short*)((char*)d_ws + 98304);   // 8*4*64*8*2  = 32768 B

    int nloc = in_sizes[0] / DD;   // 131072 locations
    prep_weights<<<128, 256, 0, stream>>>(w1, w2, b1, b2, W1bp, W2bp);
    fused_attn<<<nloc / 16, 256, 0, stream>>>(voxel, cnnf, gamma, beta, W1bp, W2bp, out);
}

// Round 5
// 85.821 us; speedup vs baseline: 1.6399x; 1.2678x over previous
//
#include <hip/hip_runtime.h>
#include <hip/hip_bf16.h>
#include <stdint.h>

#define DD 120
#define HD 15
#define LN_EPS 1e-5f

typedef __attribute__((ext_vector_type(8))) short bf16x8;
typedef __attribute__((ext_vector_type(4))) float f32x4;

__device__ __forceinline__ unsigned short f2bf(float f) {
    return __bfloat16_as_ushort(__float2bfloat16(f));
}
__device__ __forceinline__ float bf2f(unsigned short h) {
    union { unsigned u; float f; } v; v.u = ((unsigned)h) << 16;
    return v.f;
}

// ---- prep: pack weights as MFMA A-fragments with bias folded into k=120 ----
// W1bp: [24 t][4 kk][64 lane][8 e]; A-row n = padded qkv channel t*16+(lane&15)
//       tile t = part*8 + h (pos = part*128 + h*16 + i)
//       k<120: weight; k==120: bias (i<15) / 1.0 marker for V-head0-pad (part==2,h==0,i==15)
// W2bp: [8 t][4 kk][64 lane][8 e]; A-row n = out channel; k = head-padded o-channel;
//       kpad==15 carries out_b (fed by O[15]==1.0)
__global__ void prep_weights(const float* __restrict__ w1, const float* __restrict__ w2,
                             const float* __restrict__ b1, const float* __restrict__ b2,
                             unsigned short* __restrict__ W1bp, unsigned short* __restrict__ W2bp) {
    int idx = blockIdx.x * blockDim.x + threadIdx.x;
    int stride = gridDim.x * blockDim.x;
    for (int p = idx; p < 24 * 4 * 64 * 8; p += stride) {
        int e = p & 7, lane = (p >> 3) & 63, kk = (p >> 9) & 3, t = p >> 11;
        int pos = t * 16 + (lane & 15);
        int part = pos >> 7, rem = pos & 127, h = rem >> 4, i = rem & 15;
        int k = kk * 32 + (lane >> 4) * 8 + e;
        float v = 0.f;
        if (k < DD)        { if (i < HD) v = w1[(part * DD + h * HD + i) * DD + k]; }
        else if (k == DD)  { if (i < HD) v = b1[part * DD + h * HD + i];
                             else if (part == 2 && h == 0) v = 1.0f; }
        W1bp[p] = f2bf(v);
    }
    for (int p = idx; p < 8 * 4 * 64 * 8; p += stride) {
        int e = p & 7, lane = (p >> 3) & 63, kk = (p >> 9) & 3, t = p >> 11;
        int n = t * 16 + (lane & 15);
        int kpad = kk * 32 + (lane >> 4) * 8 + e;
        int i = kpad & 15;
        int h = kpad >> 4;
        float v = 0.f;
        if (n < DD) {
            if (i < HD) v = w2[n * DD + h * HD + i];
            else if (kpad == 15) v = b2[n];
        }
        W2bp[p] = f2bf(v);
    }
}

// ---- fused: 32 locations (64 tokens) per 256-thread WG; 4-way n-split ----
__global__ __launch_bounds__(256, 3) void fused_attn(
    const float* __restrict__ voxel, const float* __restrict__ cnnf,
    const float* __restrict__ gamma, const float* __restrict__ beta,
    const unsigned short* __restrict__ W1bp, const unsigned short* __restrict__ W2bp,
    float* __restrict__ out)
{
    // xs  : [64 tok][128 pos] bf16 swizzled (x; later ybuf)   16384 B
    // obuf: [64 tok][128 pos] bf16 swizzled (O)               16384 B
    __shared__ __align__(16) char smem[32768];
    unsigned short* xs   = (unsigned short*)smem;
    unsigned short* obuf = (unsigned short*)(smem + 16384);
    unsigned short* ybuf = xs;    // xs dead after B-frags are in registers (barrier-separated)

    const int tid = threadIdx.x;
    const int wave = tid >> 6, lane = tid & 63;
    const int lrow = lane & 15, lk = lane >> 4;
    const int w = wave;                 // n-split: this wave owns heads {w, w+4}
    const int r7 = lrow & 7;
    const int tok0 = blockIdx.x * 64;

    // ---- prefetch first two W1 A-tiles (hide under staging) ----
    bf16x8 A[2][4];
    #pragma unroll
    for (int kk = 0; kk < 4; ++kk) {
        A[0][kk] = *(const bf16x8*)(W1bp + ((size_t)(((0 * 8 + w) * 4 + kk) * 64 + lane)) * 8);
        A[1][kk] = *(const bf16x8*)(W1bp + ((size_t)(((1 * 8 + w) * 4 + kk) * 64 + lane)) * 8);
    }

    // ---- phase 1: stage x -> bf16 swizzled LDS (64 tokens) ----
    for (int i = tid; i < 64 * 30; i += 256) {
        int r = i / 30, c4 = i % 30;
        int gtok = tok0 + r;
        const float* src = ((gtok & 1) ? cnnf : voxel) + (size_t)(gtok >> 1) * DD + c4 * 4;
        float4 f = *(const float4*)src;
        ushort4 hv;
        hv.x = f2bf(f.x); hv.y = f2bf(f.y); hv.z = f2bf(f.z); hv.w = f2bf(f.w);
        int c8 = c4 >> 1, sub = (c4 & 1) * 8;
        *(ushort4*)((char*)xs + r * 256 + ((c8 ^ (r & 7)) << 4) + sub) = hv;
    }
    if (tid < 64) {   // pad chunk 15: x[120]=1.0 (bias channel), 121..127 = 0
        int r = tid;
        ushort4 p0; p0.x = 0x3F80; p0.y = 0; p0.z = 0; p0.w = 0;
        ushort4 z0; z0.x = 0; z0.y = 0; z0.z = 0; z0.w = 0;
        char* base = (char*)xs + r * 256 + ((15 ^ (r & 7)) << 4);
        *(ushort4*)base = p0;
        *(ushort4*)(base + 8) = z0;
    }
    __syncthreads();

    // ---- B-frags for all 4 token-tiles into registers ----
    bf16x8 bfr[4][4];
    #pragma unroll
    for (int b = 0; b < 4; ++b)
        #pragma unroll
        for (int kk = 0; kk < 4; ++kk) {
            int chunk = kk * 4 + lk;
            bfr[b][kk] = *(const bf16x8*)((const char*)xs + (b * 16 + lrow) * 256 + ((chunk ^ r7) << 4));
        }

    // ---- phase 2+3: QKV GEMM + attention, head-sequential ----
    const float scale = 0.25819888974716112567f;   // 1/sqrt(15)
    #pragma unroll
    for (int hh = 0; hh < 2; ++hh) {
        int h = w + 4 * hh;
        f32x4 acc[3][4];
        #pragma unroll
        for (int part = 0; part < 3; ++part) {
            int u = hh * 3 + part;
            #pragma unroll
            for (int b = 0; b < 4; ++b) {
                f32x4 a = {0.f, 0.f, 0.f, 0.f};
                #pragma unroll
                for (int kk = 0; kk < 4; ++kk)
                    a = __builtin_amdgcn_mfma_f32_16x16x32_bf16(A[u & 1][kk], bfr[b][kk], a, 0, 0, 0);
                acc[part][b] = a;
            }
            if (u + 2 < 6) {   // prefetch tile T[u+2] into the buffer just consumed
                int v = u + 2;
                int t2 = (v % 3) * 8 + (w + 4 * (v / 3));
                #pragma unroll
                for (int kk = 0; kk < 4; ++kk)
                    A[u & 1][kk] = *(const bf16x8*)(W1bp + ((size_t)((t2 * 4 + kk) * 64 + lane)) * 8);
            }
        }
        #pragma unroll
        for (int b = 0; b < 4; ++b) {
            f32x4 Q = acc[0][b], K = acc[1][b], V = acc[2][b];
            float kn0 = __shfl_xor(K[0], 1), kn1 = __shfl_xor(K[1], 1);
            float kn2 = __shfl_xor(K[2], 1), kn3 = __shfl_xor(K[3], 1);
            float ps = Q[0] * K[0] + Q[1] * K[1] + Q[2] * K[2] + Q[3] * K[3];
            float pn = Q[0] * kn0 + Q[1] * kn1 + Q[2] * kn2 + Q[3] * kn3;
            ps += __shfl_xor(ps, 16); ps += __shfl_xor(ps, 32);
            pn += __shfl_xor(pn, 16); pn += __shfl_xor(pn, 32);
            float s0 = ps * scale, s1 = pn * scale;
            float m = fmaxf(s0, s1);
            float e0 = __expf(s0 - m), e1 = __expf(s1 - m);
            float rr = 1.f / (e0 + e1);
            float p0 = e0 * rr, p1 = e1 * rr;
            float o0 = p0 * V[0] + p1 * __shfl_xor(V[0], 1);
            float o1 = p0 * V[1] + p1 * __shfl_xor(V[1], 1);
            float o2 = p0 * V[2] + p1 * __shfl_xor(V[2], 1);
            float o3 = p0 * V[3] + p1 * __shfl_xor(V[3], 1);
            unsigned w0 = (unsigned)f2bf(o0) | ((unsigned)f2bf(o1) << 16);
            unsigned w1v = (unsigned)f2bf(o2) | ((unsigned)f2bf(o3) << 16);
            int chunk = 2 * h + (lk >> 1);
            *(uint2*)((char*)obuf + (b * 16 + lrow) * 256 + ((chunk ^ r7) << 4) + (lk & 1) * 8)
                = make_uint2(w0, w1v);
        }
    }

    // prefetch this wave's two W2 A-tiles (t = w, w+4) before the barrier
    bf16x8 A2[2][4];
    #pragma unroll
    for (int ti = 0; ti < 2; ++ti)
        #pragma unroll
        for (int kk = 0; kk < 4; ++kk)
            A2[ti][kk] = *(const bf16x8*)(W2bp + ((size_t)(((w + 4 * ti) * 4 + kk) * 64 + lane)) * 8);
    __syncthreads();

    // ---- phase 4: out projection, 4-way n-split over 8 W2 tiles ----
    {
        bf16x8 ofr[4][4];
        #pragma unroll
        for (int b = 0; b < 4; ++b)
            #pragma unroll
            for (int kk = 0; kk < 4; ++kk) {
                int chunk = kk * 4 + lk;
                ofr[b][kk] = *(const bf16x8*)((const char*)obuf + (b * 16 + lrow) * 256 + ((chunk ^ r7) << 4));
            }
        #pragma unroll
        for (int ti = 0; ti < 2; ++ti) {
            int t = w + 4 * ti;
            int chunk = 2 * t + (lk >> 1);
            #pragma unroll
            for (int b = 0; b < 4; ++b) {
                f32x4 a = {0.f, 0.f, 0.f, 0.f};
                #pragma unroll
                for (int kk = 0; kk < 4; ++kk)
                    a = __builtin_amdgcn_mfma_f32_16x16x32_bf16(A2[ti][kk], ofr[b][kk], a, 0, 0, 0);
                unsigned w0 = (unsigned)f2bf(a[0]) | ((unsigned)f2bf(a[1]) << 16);
                unsigned w1v = (unsigned)f2bf(a[2]) | ((unsigned)f2bf(a[3]) << 16);
                *(uint2*)((char*)ybuf + (b * 16 + lrow) * 256 + ((chunk ^ r7) << 4) + (lk & 1) * 8)
                    = make_uint2(w0, w1v);
            }
        }
    }
    __syncthreads();

    // ---- phase 5: LayerNorm + mean-pool, 8 threads per location ----
    {
        int locl = tid >> 3;          // 0..31
        int s = tid & 7;              // chunk group
        int r0 = 2 * locl, r1 = r0 + 1;
        auto rd = [&](int r, int c) -> bf16x8 {
            return *(const bf16x8*)((const char*)ybuf + r * 256 + ((c ^ (r & 7)) << 4));
        };
        bf16x8 y00 = rd(r0, s), y01 = rd(r0, s + 8);
        bf16x8 y10 = rd(r1, s), y11 = rd(r1, s + 8);
        float a0[16], a1[16];
        float sum0 = 0.f, sq0 = 0.f, sum1 = 0.f, sq1 = 0.f;
        #pragma unroll
        for (int j = 0; j < 8; ++j) {
            a0[j] = bf2f((unsigned short)y00[j]); a0[8 + j] = bf2f((unsigned short)y01[j]);
            a1[j] = bf2f((unsigned short)y10[j]); a1[8 + j] = bf2f((unsigned short)y11[j]);
            sum0 += a0[j] + a0[8 + j]; sq0 += a0[j] * a0[j] + a0[8 + j] * a0[8 + j];
            sum1 += a1[j] + a1[8 + j]; sq1 += a1[j] * a1[j] + a1[8 + j] * a1[8 + j];
        }
        #pragma unroll
        for (int ww = 1; ww < 8; ww <<= 1) {
            sum0 += __shfl_xor(sum0, ww); sq0 += __shfl_xor(sq0, ww);
            sum1 += __shfl_xor(sum1, ww); sq1 += __shfl_xor(sq1, ww);
        }
        const float inv = 1.f / 120.f;
        float mu0 = sum0 * inv, mu1 = sum1 * inv;
        float var0 = sq0 * inv - mu0 * mu0, var1 = sq1 * inv - mu1 * mu1;
        float rs0 = rsqrtf(var0 + LN_EPS), rs1 = rsqrtf(var1 + LN_EPS);
        float* op = out + (size_t)(blockIdx.x * 32 + locl) * DD;
        // first 8 channels: c = 8*s (always < 120)
        {
            int c = 8 * s;
            #pragma unroll
            for (int q = 0; q < 2; ++q) {
                f32x4 gm = *(const f32x4*)(gamma + c + 4 * q);
                f32x4 bt = *(const f32x4*)(beta + c + 4 * q);
                float4 o4;
                float z0, z1;
                z0 = (a0[4 * q + 0] - mu0) * rs0; z1 = (a1[4 * q + 0] - mu1) * rs1;
                o4.x = 0.5f * (z0 + z1) * gm[0] + bt[0];
                z0 = (a0[4 * q + 1] - mu0) * rs0; z1 = (a1[4 * q + 1] - mu1) * rs1;
                o4.y = 0.5f * (z0 + z1) * gm[1] + bt[1];
                z0 = (a0[4 * q + 2] - mu0) * rs0; z1 = (a1[4 * q + 2] - mu1) * rs1;
                o4.z = 0.5f * (z0 + z1) * gm[2] + bt[2];
                z0 = (a0[4 * q + 3] - mu0) * rs0; z1 = (a1[4 * q + 3] - mu1) * rs1;
                o4.w = 0.5f * (z0 + z1) * gm[3] + bt[3];
                *(float4*)(op + c + 4 * q) = o4;
            }
        }
        // second 8 channels: c = 64 + 8*s (skip s==7: channels 120..127 are pad)
        if (s < 7) {
            int c = 64 + 8 * s;
            #pragma unroll
            for (int q = 0; q < 2; ++q) {
                f32x4 gm = *(const f32x4*)(gamma + c + 4 * q);
                f32x4 bt = *(const f32x4*)(beta + c + 4 * q);
                float4 o4;
                float z0, z1;
                z0 = (a0[8 + 4 * q + 0] - mu0) * rs0; z1 = (a1[8 + 4 * q + 0] - mu1) * rs1;
                o4.x = 0.5f * (z0 + z1) * gm[0] + bt[0];
                z0 = (a0[8 + 4 * q + 1] - mu0) * rs0; z1 = (a1[8 + 4 * q + 1] - mu1) * rs1;
                o4.y = 0.5f * (z0 + z1) * gm[1] + bt[1];
                z0 = (a0[8 + 4 * q + 2] - mu0) * rs0; z1 = (a1[8 + 4 * q + 2] - mu1) * rs1;
                o4.z = 0.5f * (z0 + z1) * gm[2] + bt[2];
                z0 = (a0[8 + 4 * q + 3] - mu0) * rs0; z1 = (a1[8 + 4 * q + 3] - mu1) * rs1;
                o4.w = 0.5f * (z0 + z1) * gm[3] + bt[3];
                *(float4*)(op + c + 4 * q) = o4;
            }
        }
    }
}

extern "C" void kernel_launch(void* const* d_in, const int* in_sizes, int n_in,
                              void* d_out, int out_size, void* d_ws, size_t ws_size,
                              hipStream_t stream) {
    const float* voxel = (const float*)d_in[0];
    const float* cnnf  = (const float*)d_in[1];
    const float* w1    = (const float*)d_in[2];
    const float* b1    = (const float*)d_in[3];
    const float* w2    = (const float*)d_in[4];
    const float* b2    = (const float*)d_in[5];
    const float* gamma = (const float*)d_in[6];
    const float* beta  = (const float*)d_in[7];
    float* out = (float*)d_out;

    unsigned short* W1bp = (unsigned short*)d_ws;                    // 24*4*64*8*2 = 98304 B
    unsigned short* W2bp = (unsigned short*)((char*)d_ws + 98304);   // 8*4*64*8*2  = 32768 B

    int nloc = in_sizes[0] / DD;   // 131072 locations
    prep_weights<<<128, 256, 0, stream>>>(w1, w2, b1, b2, W1bp, W2bp);
    fused_attn<<<nloc / 32, 256, 0, stream>>>(voxel, cnnf, gamma, beta, W1bp, W2bp, out);
}